// Round 3
// baseline (940.218 us; speedup 1.0000x reference)
//
#include <hip/hip_runtime.h>
#include <hip/hip_cooperative_groups.h>
#include <math.h>

namespace cg = cooperative_groups;

// Squeeze-Excitation, single-read persistent kernel.
// x(32,256,128,128) f32. Each of 256 blocks (1/CU) holds 4 planes (256 KiB)
// in registers, grid-syncs between pool and scale phases. x read from HBM
// exactly once; out written once. 8 chunks of 4 batches each.

#define PLANE   16384
#define PLANE4  4096
#define CH      256
#define CR      16
#define NBLK    256
#define NTHR    512
#define PPB     4        // planes per block per chunk
#define VPT     32       // float4 per thread = 128 floats
#define NCHUNK  8        // 8192 planes / (256 blk * 4)

typedef float f32x4 __attribute__((ext_vector_type(4)));

__global__ __launch_bounds__(NTHR, 2) void se_fused(
    const float* __restrict__ x,
    const float* __restrict__ w1,
    const float* __restrict__ w2,
    float* __restrict__ out,
    float* __restrict__ y)
{
    cg::grid_group grid = cg::this_grid();
    const int bid = blockIdx.x;
    const int t   = threadIdx.x;
    const int lane = t & 63, wid = t >> 6;

    __shared__ float red[8];      // one partial per wave
    __shared__ float yrow[CH];
    __shared__ float h[CR];
    __shared__ float s_sh[PPB];

    for (int ck = 0; ck < NCHUNK; ++ck) {
        const size_t plane0 = (size_t)ck * (NBLK * PPB) + (size_t)bid * PPB;
        const f32x4* xp = reinterpret_cast<const f32x4*>(x) + plane0 * PLANE4;

        // ---- load 4 planes into registers (coalesced dwordx4) ----
        f32x4 r[VPT];
#pragma unroll
        for (int k = 0; k < VPT; ++k)
            r[k] = xp[k * NTHR + t];

        // ---- per-plane mean (plane p == r[p*8 .. p*8+7]) ----
#pragma unroll
        for (int p = 0; p < PPB; ++p) {
            float sum = 0.f;
#pragma unroll
            for (int k = 0; k < 8; ++k) {
                f32x4 v = r[p * 8 + k];
                sum += (v.x + v.y) + (v.z + v.w);
            }
#pragma unroll
            for (int off = 32; off > 0; off >>= 1)
                sum += __shfl_down(sum, off, 64);
            if (lane == 0) red[wid] = sum;
            __syncthreads();
            if (t == 0) {
                float tot = 0.f;
#pragma unroll
                for (int w = 0; w < 8; ++w) tot += red[w];
                y[plane0 + p] = tot * (1.0f / (float)PLANE);
            }
            __syncthreads();
        }

        __threadfence();          // make y visible device-wide
        grid.sync();

        // ---- tiny MLP, redundant per block, for this block's 4 channels ----
        const int b  = (int)(plane0 >> 8);
        const int c0 = (int)(plane0 & 255);
        if (t < CH) yrow[t] = y[(size_t)b * CH + t];
        __syncthreads();
        if (t < CR) {
            float acc = 0.f;
#pragma unroll 8
            for (int k = 0; k < CH; ++k)
                acc += yrow[k] * w1[t * CH + k];
            h[t] = fmaxf(acc, 0.f);
        }
        __syncthreads();
        if (t < PPB) {
            float acc = 0.f;
#pragma unroll
            for (int j = 0; j < CR; ++j)
                acc += h[j] * w2[(c0 + t) * CR + j];
            s_sh[t] = 1.0f / (1.0f + expf(-acc));
        }
        __syncthreads();

        // ---- scale in-register data and store ----
        f32x4* op = reinterpret_cast<f32x4*>(out) + plane0 * PLANE4;
#pragma unroll
        for (int p = 0; p < PPB; ++p) {
            const float sc = s_sh[p];
#pragma unroll
            for (int k = 0; k < 8; ++k)
                op[(p * 8 + k) * NTHR + t] = r[p * 8 + k] * sc;
        }
        // no inter-chunk sync needed: next chunk touches disjoint y entries,
        // and s_sh/yrow/h are rewritten only after the next grid.sync().
    }
}

extern "C" void kernel_launch(void* const* d_in, const int* in_sizes, int n_in,
                              void* d_out, int out_size, void* d_ws, size_t ws_size,
                              hipStream_t stream) {
    const float* x  = (const float*)d_in[0];
    const float* w1 = (const float*)d_in[1];
    const float* w2 = (const float*)d_in[2];
    float* out = (float*)d_out;
    float* y   = (float*)d_ws;        // 8192 floats

    void* args[] = { (void*)&x, (void*)&w1, (void*)&w2, (void*)&out, (void*)&y };
    hipLaunchCooperativeKernel((void*)se_fused, dim3(NBLK), dim3(NTHR),
                               args, 0, stream);
}

// Round 4
// 403.376 us; speedup vs baseline: 2.3309x; 2.3309x over previous
//
#include <hip/hip_runtime.h>
#include <math.h>

// Squeeze-Excitation, single-HBM-read persistent kernel, manual grid barrier.
// x(32,256,128,128) f32. 256 blocks (1/CU) x 512 thr; each thread holds
// 32 float4 (128 VGPR) = 4 planes/block. 8 chunks; one inline grid barrier
// per chunk (atomicAdd + agent-scope spin — NO function call, so registers
// stay live across it; cg::sync spilled everything in R3).

#define PLANE   16384
#define PLANE4  4096
#define CH      256
#define CR      16
#define NBLK    256
#define NTHR    512
#define PPB     4        // planes per block per chunk
#define VPT     32       // float4 per thread
#define NCHUNK  8

typedef float f32x4 __attribute__((ext_vector_type(4)));

__global__ __launch_bounds__(NTHR, 2) void se_fused(
    const float* __restrict__ x,
    const float* __restrict__ w1,
    const float* __restrict__ w2,
    float* __restrict__ out,
    float* __restrict__ y,
    unsigned* __restrict__ bar)
{
    const int bid = blockIdx.x;
    const int t   = threadIdx.x;
    const int lane = t & 63, wid = t >> 6;

    __shared__ float red[PPB][8];
    __shared__ float yrow[CH];
    __shared__ float h[CR];
    __shared__ float s_sh[PPB];

    for (int ck = 0; ck < NCHUNK; ++ck) {
        const size_t plane0 = (size_t)ck * (NBLK * PPB) + (size_t)bid * PPB;
        const f32x4* xp = reinterpret_cast<const f32x4*>(x) + plane0 * PLANE4;

        // ---- load 4 planes into registers (stays in VGPRs: no calls below) --
        f32x4 r[VPT];
#pragma unroll
        for (int k = 0; k < VPT; ++k)
            r[k] = xp[(size_t)k * NTHR + t];

        // ---- per-plane means ----
#pragma unroll
        for (int p = 0; p < PPB; ++p) {
            float sum = 0.f;
#pragma unroll
            for (int k = 0; k < 8; ++k) {
                f32x4 v = r[p * 8 + k];
                sum += (v.x + v.y) + (v.z + v.w);
            }
#pragma unroll
            for (int off = 32; off > 0; off >>= 1)
                sum += __shfl_down(sum, off, 64);
            if (lane == 0) red[p][wid] = sum;
        }
        __syncthreads();
        if (t < PPB) {
            float tot = 0.f;
#pragma unroll
            for (int w = 0; w < 8; ++w) tot += red[t][w];
            // agent-scope store: visible across XCDs (bypasses local L2)
            __hip_atomic_store(&y[plane0 + t], tot * (1.0f / (float)PLANE),
                               __ATOMIC_RELAXED, __HIP_MEMORY_SCOPE_AGENT);
        }

        // ---- inline grid barrier, phase ck+1 (monotonic counter) ----
        __syncthreads();
        if (t == 0) {
            __threadfence();                         // release y
            atomicAdd(bar, 1u);                      // device-scope arrive
            const unsigned target = (unsigned)(ck + 1) * NBLK;
            while (__hip_atomic_load(bar, __ATOMIC_ACQUIRE,
                                     __HIP_MEMORY_SCOPE_AGENT) < target)
                __builtin_amdgcn_s_sleep(8);
        }
        __syncthreads();

        // ---- tiny MLP for this block's 4 channels (redundant per block) ----
        const int b  = (int)(plane0 >> 8);
        const int c0 = (int)(plane0 & 255);
        if (t < CH)
            yrow[t] = __hip_atomic_load(&y[(size_t)b * CH + t],
                                        __ATOMIC_RELAXED, __HIP_MEMORY_SCOPE_AGENT);
        __syncthreads();
        if (t < CR) {
            float acc = 0.f;
#pragma unroll 8
            for (int k = 0; k < CH; ++k)
                acc += yrow[k] * w1[t * CH + k];
            h[t] = fmaxf(acc, 0.f);
        }
        __syncthreads();
        if (t < PPB) {
            float acc = 0.f;
#pragma unroll
            for (int j = 0; j < CR; ++j)
                acc += h[j] * w2[(c0 + t) * CR + j];
            s_sh[t] = 1.0f / (1.0f + expf(-acc));
        }
        __syncthreads();

        // ---- scale register-held data, store ----
        f32x4* op = reinterpret_cast<f32x4*>(out) + plane0 * PLANE4;
#pragma unroll
        for (int p = 0; p < PPB; ++p) {
            const float sc = s_sh[p];
#pragma unroll
            for (int k = 0; k < 8; ++k)
                op[(size_t)(p * 8 + k) * NTHR + t] = r[p * 8 + k] * sc;
        }
        __syncthreads();   // LDS reuse guard before next chunk
    }
}

extern "C" void kernel_launch(void* const* d_in, const int* in_sizes, int n_in,
                              void* d_out, int out_size, void* d_ws, size_t ws_size,
                              hipStream_t stream) {
    const float* x  = (const float*)d_in[0];
    const float* w1 = (const float*)d_in[1];
    const float* w2 = (const float*)d_in[2];
    float* out = (float*)d_out;

    float*    y   = (float*)d_ws;                  // 8192 floats
    unsigned* bar = (unsigned*)((char*)d_ws + 8192 * sizeof(float));

    hipMemsetAsync(bar, 0, sizeof(unsigned), stream);   // capture-safe

    void* args[] = { (void*)&x, (void*)&w1, (void*)&w2, (void*)&out,
                     (void*)&y, (void*)&bar };
    hipLaunchCooperativeKernel((void*)se_fused, dim3(NBLK), dim3(NTHR),
                               args, 0, stream);
}

// Round 5
// 342.657 us; speedup vs baseline: 2.7439x; 1.1772x over previous
//
#include <hip/hip_runtime.h>
#include <math.h>

// Squeeze-Excitation, single-HBM-read persistent kernel, LDS-resident data.
// x(32,256,128,128) f32. 256 blocks (1/CU, cooperative) x 512 thr.
// Per chunk a block holds 2 planes (128 KiB) in LDS (survives sync, unlike
// VGPRs which the compiler spilled in R3/R4). 16 chunks; per-batch 128-block
// sub-barrier (atomic counter). global_load_lds DMA; raw s_barrier at chunk
// end so output stores overlap next chunk's DMA.

#define CH     256
#define CR     16
#define NBLK   256
#define NTHR   512
#define NCHUNK 16
#define KPT    16      // f32x4 DMA issues per thread (2 planes / 512 thr)
#define PL4    4096    // f32x4 per plane

typedef float f32x4 __attribute__((ext_vector_type(4)));
#define AS1 __attribute__((address_space(1)))
#define AS3 __attribute__((address_space(3)))

__global__ __launch_bounds__(NTHR, 1) void se_fused(
    const float* __restrict__ x,
    const float* __restrict__ w1,
    const float* __restrict__ w2,
    float* __restrict__ out,
    float* __restrict__ y,
    unsigned* __restrict__ ready)
{
    const int bid  = blockIdx.x;
    const int t    = threadIdx.x;
    const int lane = t & 63, wid = t >> 6;

    __shared__ f32x4 buf[2 * PL4];          // 128 KiB: 2 planes
    __shared__ float red[2][8];
    __shared__ float yrow[CH];
    __shared__ float h[CR];
    __shared__ float s_sh[2];

    // ---- prologue: DMA chunk 0 ----
    {
        const int b = (bid >> 7);           // ck=0
        const int c0 = (bid & 127) * 2;
        const AS1 f32x4* g4 = (const AS1 f32x4*)x + ((size_t)b * CH + c0) * PL4;
#pragma unroll
        for (int k = 0; k < KPT; ++k)
            __builtin_amdgcn_global_load_lds(
                (const AS1 void*)(g4 + (k * NTHR + t)),
                (AS3 void*)(&buf[k * NTHR + (wid << 6)]), 16, 0, 0);
    }

    for (int ck = 0; ck < NCHUNK; ++ck) {
        const int b  = 2 * ck + (bid >> 7);
        const int c0 = (bid & 127) * 2;

        // ---- wait this chunk's DMA (and residual stores), all waves ----
        asm volatile("s_waitcnt vmcnt(0)" ::: "memory");
        __builtin_amdgcn_s_barrier();

        // ---- per-plane sums from LDS ----
        float sA = 0.f, sB = 0.f;
#pragma unroll
        for (int k = 0; k < 8; ++k) {
            f32x4 v = buf[k * NTHR + t];
            sA += (v.x + v.y) + (v.z + v.w);
        }
#pragma unroll
        for (int k = 8; k < 16; ++k) {
            f32x4 v = buf[k * NTHR + t];
            sB += (v.x + v.y) + (v.z + v.w);
        }
#pragma unroll
        for (int off = 32; off; off >>= 1) {
            sA += __shfl_down(sA, off, 64);
            sB += __shfl_down(sB, off, 64);
        }
        if (lane == 0) { red[0][wid] = sA; red[1][wid] = sB; }
        __syncthreads();

        // ---- y store + release + arrive + spin (thread 0) ----
        if (t == 0) {
            float tA = 0.f, tB = 0.f;
#pragma unroll
            for (int w = 0; w < 8; ++w) { tA += red[0][w]; tB += red[1][w]; }
            const size_t p0 = (size_t)b * CH + c0;
            __hip_atomic_store(&y[p0],     tA * (1.f / 16384.f),
                               __ATOMIC_RELAXED, __HIP_MEMORY_SCOPE_AGENT);
            __hip_atomic_store(&y[p0 + 1], tB * (1.f / 16384.f),
                               __ATOMIC_RELAXED, __HIP_MEMORY_SCOPE_AGENT);
            asm volatile("s_waitcnt vmcnt(0)" ::: "memory");   // y visible
            __hip_atomic_fetch_add(&ready[b], 1u,
                                   __ATOMIC_RELAXED, __HIP_MEMORY_SCOPE_AGENT);
            while (__hip_atomic_load(&ready[b], __ATOMIC_RELAXED,
                                     __HIP_MEMORY_SCOPE_AGENT) < 128u)
                __builtin_amdgcn_s_sleep(2);
        }
        __syncthreads();

        // ---- yrow for batch b ----
        if (t < CH)
            yrow[t] = __hip_atomic_load(&y[(size_t)b * CH + t],
                                        __ATOMIC_RELAXED, __HIP_MEMORY_SCOPE_AGENT);
        __syncthreads();

        // ---- h = relu(yrow @ w1^T): 16 lanes per h[j] ----
        if (t < CH) {
            const int j = t >> 4, i = t & 15;
            float part = 0.f;
#pragma unroll
            for (int m = 0; m < 16; ++m)
                part += yrow[i * 16 + m] * w1[j * CH + i * 16 + m];
#pragma unroll
            for (int off = 8; off; off >>= 1)
                part += __shfl_down(part, off, 64);
            if (i == 0) h[j] = fmaxf(part, 0.f);
        }
        __syncthreads();

        // ---- s = sigmoid(h @ w2^T) for this block's 2 channels ----
        if (t < 2) {
            float acc = 0.f;
#pragma unroll
            for (int q = 0; q < CR; ++q)
                acc += h[q] * w2[(c0 + t) * CR + q];
            s_sh[t] = 1.f / (1.f + expf(-acc));
        }
        __syncthreads();

        // ---- scale from LDS, store to out ----
        {
            f32x4* o4 = (f32x4*)out + ((size_t)b * CH + c0) * PL4;
            const float scA = s_sh[0], scB = s_sh[1];
#pragma unroll
            for (int k = 0; k < 16; ++k) {
                f32x4 v = buf[k * NTHR + t];
                o4[k * NTHR + t] = v * (k < 8 ? scA : scB);
            }
        }

        // ---- release buf for next DMA: LDS reads done, stores keep flying --
        asm volatile("s_waitcnt lgkmcnt(0)" ::: "memory");
        __builtin_amdgcn_s_barrier();

        if (ck + 1 < NCHUNK) {
            const int bn  = 2 * (ck + 1) + (bid >> 7);
            const AS1 f32x4* g4 = (const AS1 f32x4*)x + ((size_t)bn * CH + c0) * PL4;
#pragma unroll
            for (int k = 0; k < KPT; ++k)
                __builtin_amdgcn_global_load_lds(
                    (const AS1 void*)(g4 + (k * NTHR + t)),
                    (AS3 void*)(&buf[k * NTHR + (wid << 6)]), 16, 0, 0);
        }
    }
}

extern "C" void kernel_launch(void* const* d_in, const int* in_sizes, int n_in,
                              void* d_out, int out_size, void* d_ws, size_t ws_size,
                              hipStream_t stream) {
    const float* x  = (const float*)d_in[0];
    const float* w1 = (const float*)d_in[1];
    const float* w2 = (const float*)d_in[2];
    float* out = (float*)d_out;

    float*    y     = (float*)d_ws;                              // 8192 f32
    unsigned* ready = (unsigned*)((char*)d_ws + 8192 * sizeof(float)); // 32 u32

    hipMemsetAsync(ready, 0, 32 * sizeof(unsigned), stream);     // capture-safe

    void* args[] = { (void*)&x, (void*)&w1, (void*)&w2, (void*)&out,
                     (void*)&y, (void*)&ready };
    hipLaunchCooperativeKernel((void*)se_fused, dim3(NBLK), dim3(NTHR),
                               args, 0, stream);
}